// Round 5
// baseline (28.416 us; speedup 1.0000x reference)
//
#include <hip/hip_runtime.h>

// SmartCNN round 5: persistent grid-stride quads + pairwise post-ReLU table.
//
// vs round 4 (25.0 us) / round 3 (24.3 us):
//  - independent per-lane board load (4 loads, all in the board's single 64B
//    line -> L1 broadcast) instead of the serial shfl-assembly chain
//  - persistent blocks (2048 x 256), grid-stride over board-quads: table
//    init amortized over 2 tasks/thread, and the 2nd iteration's loads
//    overlap the 1st iteration's gather/store drain (ILP across tasks)
//  - pairwise table kept: out = tab[(flip,o,e1,e2)], 24 ds_read_b32/lane

__device__ __forceinline__ int chmap(int e, int fv, int fh) {
    if (e == 0) return fv ? 0 : 1;   // empty channel (swaps with mask if fv)
    if (e == 1) return fh ? 3 : 2;   // class1/class2 swap if fh
    if (e == 2) return fh ? 2 : 3;
    return 1 + e;
}

__global__ __launch_bounds__(256) void smartcnn_kernel(
    const float* __restrict__ x,
    const float* __restrict__ W0,
    const float* __restrict__ b0,
    const float* __restrict__ W1,
    float* __restrict__ out,
    int nquads)
{
    __shared__ float tabH[1936];   // [flip*4+o][e1][e2] : relu(C0 + t0h[e1] + t1h[e2])
    __shared__ float tabV[1936];
    __shared__ float sW0[96], sW1[96], sb0[4];

    const int t = threadIdx.x;
    if (t < 96) { sW0[t] = W0[t]; sW1[t] = W1[t]; }
    if (t < 4)  sb0[t] = b0[t];
    __syncthreads();

#pragma unroll
    for (int k = 0; k < 8; ++k) {
        int id = t + k * 256;
        if (id < 1936) {
            int e2 = id % 11;
            int r  = id / 11;
            int e1 = r % 11;
            int fo = r / 11;             // flip*4 + o
            int o = fo & 3, flip = fo >> 2;
            int fvv = flip >> 1, fhh = flip & 1;
            int ch1 = chmap(e1, fvv, fhh);
            int ch2 = chmap(e2, fvv, fhh);
            int mc2 = fvv ? 2 : 0;
            int o24 = o * 24;
            float C0 = sb0[o] + sW0[o24 + mc2] + sW0[o24 + mc2 + 1];
            float C1 =          sW1[o24 + mc2] + sW1[o24 + mc2 + 1];
            tabH[id] = fmaxf(C0 + sW0[o24 + ch1 * 2] + sW0[o24 + ch2 * 2 + 1], 0.0f);
            tabV[id] = fmaxf(C1 + sW1[o24 + ch1 * 2] + sW1[o24 + ch2 * 2 + 1], 0.0f);
        }
    }
    __syncthreads();

    const int stride = gridDim.x * 256;
    for (int gq = blockIdx.x * 256 + t; gq < nquads; gq += stride) {
        const int b = gq >> 2;    // board
        const int q = gq & 3;     // output float4 column within each 64B line

        // board load: 4 float4s, all within the board's single 64B line
        const float4* x4 = (const float4*)x + (size_t)b * 4;
        float4 r0 = x4[0], r1 = x4[1], r2 = x4[2], r3 = x4[3];

        // pack log2-classes as nibbles (rows 0,1 in pk0; rows 2,3 in pk1)
#define EV(v) (max((int)(__float_as_uint(v) >> 23) - 127, 0))
        unsigned pk0 = (unsigned)EV(r0.x)        | ((unsigned)EV(r0.y) << 4)  |
                       ((unsigned)EV(r0.z) << 8)  | ((unsigned)EV(r0.w) << 12) |
                       ((unsigned)EV(r1.x) << 16) | ((unsigned)EV(r1.y) << 20) |
                       ((unsigned)EV(r1.z) << 24) | ((unsigned)EV(r1.w) << 28);
        unsigned pk1 = (unsigned)EV(r2.x)        | ((unsigned)EV(r2.y) << 4)  |
                       ((unsigned)EV(r2.z) << 8)  | ((unsigned)EV(r2.w) << 12) |
                       ((unsigned)EV(r3.x) << 16) | ((unsigned)EV(r3.y) << 20) |
                       ((unsigned)EV(r3.z) << 24) | ((unsigned)EV(r3.w) << 28);
#undef EV

        // corner argmax (classes monotone in value; first-max-wins preserved)
        int e00 = pk0 & 15, e03 = (pk0 >> 12) & 15;
        int e30 = (pk1 >> 16) & 15, e33 = (int)(pk1 >> 28);
        int best = e00, ix = 0;
        if (e03 > best) { best = e03; ix = 1; }
        if (e30 > best) { best = e30; ix = 2; }
        if (e33 > best) { best = e33; ix = 3; }
        const int fv = ix >> 1, fh = ix & 1;

        // normalize packs to the flipped board
        unsigned fva = (pk1 >> 16) | (pk1 << 16);   // rows 3,2
        unsigned fvb = (pk0 >> 16) | (pk0 << 16);   // rows 1,0
        pk0 = fv ? fva : pk0;
        pk1 = fv ? fvb : pk1;
        unsigned ra = ((pk0 & 0x0F0F0F0Fu) << 4) | ((pk0 >> 4) & 0x0F0F0F0Fu);
        ra = ((ra & 0x00FF00FFu) << 8) | ((ra >> 8) & 0x00FF00FFu);
        unsigned rb = ((pk1 & 0x0F0F0F0Fu) << 4) | ((pk1 >> 4) & 0x0F0F0F0Fu);
        rb = ((rb & 0x00FF00FFu) << 8) | ((rb >> 8) & 0x00FF00FFu);
        pk0 = fh ? ra : pk0;
        pk1 = fh ? rb : pk1;

        const unsigned long long pk =
            ((unsigned long long)pk1 << 32) | (unsigned long long)pk0;
#define EX(c) ((int)((pk >> ((c) * 4)) & 15ull))

        float4* out4 = (float4*)out + (size_t)b * 24;

#pragma unroll
        for (int rp = 0; rp < 3; ++rp) {
            int n = rp * 4 + q;           // float4 index within 48-float half
            int o = (n * 11) >> 5;        // n/3
            int s = n - 3 * o;            // sub-row 0..2
            int f1 = (s == 2) ? 1 : 0;
            int f2 = (s >= 1) ? 1 : 0;
            int s5 = s * 5;
            int base = (ix * 4 + o) * 121;

            // zh float4: table on horizontally-adjacent cells (c, c+1)
            int c0 = s5, c1 = s5 + 1 + f1, c2 = s5 + 2 + f2, c3 = s5 + 4;
            float4 vh;
            vh.x = tabH[base + EX(c0) * 11 + EX(c0 + 1)];
            vh.y = tabH[base + EX(c1) * 11 + EX(c1 + 1)];
            vh.z = tabH[base + EX(c2) * 11 + EX(c2 + 1)];
            vh.w = tabH[base + EX(c3) * 11 + EX(c3 + 1)];
            out4[rp * 4 + q] = vh;

            // zv^T float4: vertically-adjacent cells (d, d+4)
            int d0 = s5, d1 = s5 + 4 - 11 * f1, d2 = s5 + 8 - 11 * f2, d3 = s5 + 1;
            float4 vv;
            vv.x = tabV[base + EX(d0) * 11 + EX(d0 + 4)];
            vv.y = tabV[base + EX(d1) * 11 + EX(d1 + 4)];
            vv.z = tabV[base + EX(d2) * 11 + EX(d2 + 4)];
            vv.w = tabV[base + EX(d3) * 11 + EX(d3 + 4)];
            out4[12 + rp * 4 + q] = vv;
        }
#undef EX
    }
}

extern "C" void kernel_launch(void* const* d_in, const int* in_sizes, int n_in,
                              void* d_out, int out_size, void* d_ws, size_t ws_size,
                              hipStream_t stream) {
    const float* x  = (const float*)d_in[0];
    const float* W0 = (const float*)d_in[1];
    const float* b0 = (const float*)d_in[2];
    const float* W1 = (const float*)d_in[3];
    float* out = (float*)d_out;

    int B = in_sizes[0] / 16;
    int nquads = B * 4;                          // 4 lanes per board
    int blocks = 2048;                           // persistent; ~2 tasks/thread
    int need = (nquads + 255) / 256;
    if (blocks > need) blocks = need;
    smartcnn_kernel<<<blocks, 256, 0, stream>>>(x, W0, b0, W1, out, nquads);
}